// Round 3
// baseline (163.600 us; speedup 1.0000x reference)
//
#include <hip/hip_runtime.h>

// TT Q-gather, stage-through-LDS, fully hand-unrolled (no runtime-indexed
// private arrays -> no scratch).
//   vec = V01[s0][s1][:]                (precomputed G0*G1 fold, 2MB in ws)
//   for k in 2..5: vec = vec @ Gk[:,sk,:]   (Gk staged in LDS, XOR-swizzled)
//   q   = vec . U67[s6][a][:]           (precomputed G6*G7 fold, 2MB in ws)
//
// LDS layout: matrix n occupies float4 slots [n*16 .. n*16+15]; logical
// chunk c = 2r+h stored at slot c ^ (n&15) -> gather lanes with random n
// spread over all 8 bank-phases.

#define NN 256
#define RR 8
#define NR 2048   // N * R

__global__ __launch_bounds__(256) void build_tables(
    const float* __restrict__ G0, const float* __restrict__ G1,
    const float* __restrict__ G6, const float* __restrict__ G7,
    float* __restrict__ V01, float* __restrict__ U67) {
    const int t = threadIdx.x;
    if (blockIdx.x < NN) {
        // V01[n0][n1][s] = sum_r G0[n0,r] * G1[r,n1,s]
        const int n0 = blockIdx.x, n1 = t;
        float acc[RR] = {0.f,0.f,0.f,0.f,0.f,0.f,0.f,0.f};
#pragma unroll
        for (int r = 0; r < RR; ++r) {
            float ar = G0[n0 * RR + r];
            const float4* p = (const float4*)(G1 + r * NR + n1 * RR);
            float4 x = p[0], y = p[1];
            acc[0] += ar * x.x; acc[1] += ar * x.y;
            acc[2] += ar * x.z; acc[3] += ar * x.w;
            acc[4] += ar * y.x; acc[5] += ar * y.y;
            acc[6] += ar * y.z; acc[7] += ar * y.w;
        }
        float4* o = (float4*)(V01 + n0 * NR + n1 * RR);
        o[0] = make_float4(acc[0], acc[1], acc[2], acc[3]);
        o[1] = make_float4(acc[4], acc[5], acc[6], acc[7]);
    } else {
        // U67[n6][n7][r] = sum_s G6[r,n6,s] * G7[s,n7]
        const int n6 = blockIdx.x - NN, n7 = t;
        float g7v[RR];
#pragma unroll
        for (int s = 0; s < RR; ++s) g7v[s] = G7[s * NN + n7];
        float u[RR];
#pragma unroll
        for (int r = 0; r < RR; ++r) {
            float acc = 0.f;
#pragma unroll
            for (int s = 0; s < RR; ++s)
                acc += G6[r * NR + n6 * RR + s] * g7v[s];
            u[r] = acc;
        }
        float4* o = (float4*)(U67 + n6 * NR + n7 * RR);
        o[0] = make_float4(u[0], u[1], u[2], u[3]);
        o[1] = make_float4(u[4], u[5], u[6], u[7]);
    }
}

// --- tt_main macros: everything unrolled, all state in named registers ---

// issue global loads for core G into fx/fy (4 rows of (r,n) per thread)
#define FETCH(Gp)                                                           \
    do {                                                                    \
        _Pragma("unroll") for (int i = 0; i < 4; ++i) {                     \
            int pidx = t + (i << 9);                                        \
            const float4* gp =                                              \
                (const float4*)((Gp) + ((pidx >> 8) * NR) +                 \
                                ((pidx & 255) * RR));                       \
            fx[i] = gp[0];                                                  \
            fy[i] = gp[1];                                                  \
        }                                                                   \
    } while (0)

// commit fetched registers into swizzled LDS (barriers on both sides)
#define COMMIT()                                                            \
    do {                                                                    \
        __syncthreads();                                                    \
        _Pragma("unroll") for (int i = 0; i < 4; ++i) {                     \
            int pidx = t + (i << 9);                                        \
            int r = pidx >> 8;                                              \
            int n = pidx & 255;                                             \
            int xm = n & 15;                                                \
            lds[(n << 4) + ((2 * r) ^ xm)]     = fx[i];                     \
            lds[(n << 4) + ((2 * r + 1) ^ xm)] = fy[i];                     \
        }                                                                   \
        __syncthreads();                                                    \
    } while (0)

// gather matrix nidx from LDS and do v = v @ M
#define GATHER(nidx)                                                        \
    do {                                                                    \
        const float4* mp = lds + ((nidx) << 4);                             \
        int xm = (nidx) & 15;                                               \
        float nv0 = 0.f, nv1 = 0.f, nv2 = 0.f, nv3 = 0.f;                   \
        float nv4 = 0.f, nv5 = 0.f, nv6 = 0.f, nv7 = 0.f;                   \
        _Pragma("unroll") for (int r = 0; r < 8; ++r) {                     \
            float4 x = mp[(2 * r) ^ xm];                                    \
            float4 y = mp[(2 * r + 1) ^ xm];                                \
            float vr = v[r];                                                \
            nv0 += vr * x.x; nv1 += vr * x.y;                               \
            nv2 += vr * x.z; nv3 += vr * x.w;                               \
            nv4 += vr * y.x; nv5 += vr * y.y;                               \
            nv6 += vr * y.z; nv7 += vr * y.w;                               \
        }                                                                   \
        v[0] = nv0; v[1] = nv1; v[2] = nv2; v[3] = nv3;                     \
        v[4] = nv4; v[5] = nv5; v[6] = nv6; v[7] = nv7;                     \
    } while (0)

__global__ __launch_bounds__(512, 4) void tt_main(
    const float* __restrict__ G2, const float* __restrict__ G3,
    const float* __restrict__ G4, const float* __restrict__ G5,
    const float* __restrict__ V01, const float* __restrict__ U67,
    const int* __restrict__ states, const int* __restrict__ actions,
    float* __restrict__ out, int B) {
    __shared__ float4 lds[NN * 16];   // 64 KB

    const int t = threadIdx.x;
    const int b = blockIdx.x * 512 + t;
    const bool active = (b < B);
    const int bc = active ? b : 0;

    const int* srow = states + bc * 7;
    const int s0 = srow[0];
    const int s1 = srow[1];
    const int s2 = srow[2];
    const int s3 = srow[3];
    const int s4 = srow[4];
    const int s5 = srow[5];
    const int s6 = srow[6];
    const int a7 = actions[bc];

    float v[8];
    {
        const float4* p = (const float4*)(V01 + s0 * NR + s1 * RR);
        float4 x = p[0], y = p[1];
        v[0] = x.x; v[1] = x.y; v[2] = x.z; v[3] = x.w;
        v[4] = y.x; v[5] = y.y; v[6] = y.z; v[7] = y.w;
    }

    float4 fx[4], fy[4];

    FETCH(G2);
    COMMIT();            // LDS = G2
    FETCH(G3);           // G3 loads fly while we gather G2
    GATHER(s2);
    COMMIT();            // LDS = G3
    FETCH(G4);
    GATHER(s3);
    COMMIT();            // LDS = G4
    FETCH(G5);
    GATHER(s4);
    COMMIT();            // LDS = G5
    GATHER(s5);

    // q = v . U67[s6][a7][:]
    const float4* p = (const float4*)(U67 + s6 * NR + a7 * RR);
    float4 x = p[0], y = p[1];
    float q = v[0] * x.x + v[1] * x.y + v[2] * x.z + v[3] * x.w
            + v[4] * y.x + v[5] * y.y + v[6] * y.z + v[7] * y.w;
    if (active) out[b] = q;
}

extern "C" void kernel_launch(void* const* d_in, const int* in_sizes, int n_in,
                              void* d_out, int out_size, void* d_ws, size_t ws_size,
                              hipStream_t stream) {
    const float* G0 = (const float*)d_in[0];
    const float* G1 = (const float*)d_in[1];
    const float* G2 = (const float*)d_in[2];
    const float* G3 = (const float*)d_in[3];
    const float* G4 = (const float*)d_in[4];
    const float* G5 = (const float*)d_in[5];
    const float* G6 = (const float*)d_in[6];
    const float* G7 = (const float*)d_in[7];
    const int* states  = (const int*)d_in[8];
    const int* actions = (const int*)d_in[9];
    float* out = (float*)d_out;
    int B = in_sizes[9];

    float* V01 = (float*)d_ws;            // 256*256*8 floats = 2 MB
    float* U67 = V01 + NN * NN * RR;      // 2 MB

    hipLaunchKernelGGL(build_tables, dim3(2 * NN), dim3(256), 0, stream,
                       G0, G1, G6, G7, V01, U67);

    int nblocks = (B + 511) / 512;
    hipLaunchKernelGGL(tt_main, dim3(nblocks), dim3(512), 0, stream,
                       G2, G3, G4, G5, V01, U67, states, actions, out, B);
}

// Round 4
// 133.797 us; speedup vs baseline: 1.2228x; 1.2228x over previous
//
#include <hip/hip_runtime.h>

// TT Q-gather, stage-through-LDS, hand-unrolled, NO register prefetch
// (round-3's fx[]/fy[] double-buffer spilled to scratch: 234MB WRITE_SIZE).
//   vec = V01[s0][s1][:]                (precomputed G0*G1 fold, 2MB in ws)
//   for k in 2..5: vec = vec @ Gk[:,sk,:]   (Gk staged in LDS, XOR-swizzled)
//   q   = vec . U67[s6][a][:]           (precomputed G6*G7 fold, 2MB in ws)
//
// LDS layout: matrix n occupies float4 slots [n*16 .. n*16+15]; logical
// chunk c = 2r+h stored at slot c ^ (n&15) -> gather lanes with random n
// spread uniformly over all 8 bank-phases (measured +2cy/instr over floor).
// The same 64KB buffer is used first to stage the block's `states` rows.

#define NN 256
#define RR 8
#define NR 2048   // N * R

__global__ __launch_bounds__(256) void build_tables(
    const float* __restrict__ G0, const float* __restrict__ G1,
    const float* __restrict__ G6, const float* __restrict__ G7,
    float* __restrict__ V01, float* __restrict__ U67) {
    const int t = threadIdx.x;
    if (blockIdx.x < NN) {
        // V01[n0][n1][s] = sum_r G0[n0,r] * G1[r,n1,s]
        const int n0 = blockIdx.x, n1 = t;
        float acc[RR] = {0.f,0.f,0.f,0.f,0.f,0.f,0.f,0.f};
#pragma unroll
        for (int r = 0; r < RR; ++r) {
            float ar = G0[n0 * RR + r];
            const float4* p = (const float4*)(G1 + r * NR + n1 * RR);
            float4 x = p[0], y = p[1];
            acc[0] += ar * x.x; acc[1] += ar * x.y;
            acc[2] += ar * x.z; acc[3] += ar * x.w;
            acc[4] += ar * y.x; acc[5] += ar * y.y;
            acc[6] += ar * y.z; acc[7] += ar * y.w;
        }
        float4* o = (float4*)(V01 + n0 * NR + n1 * RR);
        o[0] = make_float4(acc[0], acc[1], acc[2], acc[3]);
        o[1] = make_float4(acc[4], acc[5], acc[6], acc[7]);
    } else {
        // U67[n6][n7][r] = sum_s G6[r,n6,s] * G7[s,n7]
        const int n6 = blockIdx.x - NN, n7 = t;
        float g7v[RR];
#pragma unroll
        for (int s = 0; s < RR; ++s) g7v[s] = G7[s * NN + n7];
        float u[RR];
#pragma unroll
        for (int r = 0; r < RR; ++r) {
            float acc = 0.f;
#pragma unroll
            for (int s = 0; s < RR; ++s)
                acc += G6[r * NR + n6 * RR + s] * g7v[s];
            u[r] = acc;
        }
        float4* o = (float4*)(U67 + n6 * NR + n7 * RR);
        o[0] = make_float4(u[0], u[1], u[2], u[3]);
        o[1] = make_float4(u[4], u[5], u[6], u[7]);
    }
}

// stage core G into swizzled LDS; fused load->store, 2 float4 live at a time
#define STAGE(Gp)                                                           \
    do {                                                                    \
        __syncthreads();                                                    \
        _Pragma("unroll") for (int i = 0; i < 4; ++i) {                     \
            int pidx = t + (i << 9);                                        \
            int r = pidx >> 8;                                              \
            int n = pidx & 255;                                             \
            const float4* gp = (const float4*)((Gp) + r * NR + n * RR);     \
            float4 x = gp[0];                                               \
            float4 y = gp[1];                                               \
            int xm = n & 15;                                                \
            lds[(n << 4) + ((2 * r) ^ xm)]     = x;                         \
            lds[(n << 4) + ((2 * r + 1) ^ xm)] = y;                         \
        }                                                                   \
        __syncthreads();                                                    \
    } while (0)

// gather matrix nidx from LDS and do v = v @ M
#define GATHER(nidx)                                                        \
    do {                                                                    \
        const float4* mp = lds + ((nidx) << 4);                             \
        int xm = (nidx) & 15;                                               \
        float nv0 = 0.f, nv1 = 0.f, nv2 = 0.f, nv3 = 0.f;                   \
        float nv4 = 0.f, nv5 = 0.f, nv6 = 0.f, nv7 = 0.f;                   \
        _Pragma("unroll") for (int r = 0; r < 8; ++r) {                     \
            float4 x = mp[(2 * r) ^ xm];                                    \
            float4 y = mp[(2 * r + 1) ^ xm];                                \
            float vr = v[r];                                                \
            nv0 += vr * x.x; nv1 += vr * x.y;                               \
            nv2 += vr * x.z; nv3 += vr * x.w;                               \
            nv4 += vr * y.x; nv5 += vr * y.y;                               \
            nv6 += vr * y.z; nv7 += vr * y.w;                               \
        }                                                                   \
        v[0] = nv0; v[1] = nv1; v[2] = nv2; v[3] = nv3;                     \
        v[4] = nv4; v[5] = nv5; v[6] = nv6; v[7] = nv7;                     \
    } while (0)

__global__ __launch_bounds__(512, 4) void tt_main(
    const float* __restrict__ G2, const float* __restrict__ G3,
    const float* __restrict__ G4, const float* __restrict__ G5,
    const float* __restrict__ V01, const float* __restrict__ U67,
    const int* __restrict__ states, const int* __restrict__ actions,
    float* __restrict__ out, int B) {
    __shared__ float4 lds[NN * 16];   // 64 KB -> 2 blocks/CU

    const int t = threadIdx.x;
    const int b = blockIdx.x * 512 + t;
    const bool active = (b < B);
    const int bc = active ? b : 0;

    // --- stage this block's states rows through LDS (coalesced) ---
    {
        int* ibuf = (int*)lds;
        const int* gsrc = states + (size_t)blockIdx.x * 512 * 7;
        const int lim = B * 7 - blockIdx.x * 512 * 7;   // valid ints remaining
#pragma unroll
        for (int k = 0; k < 7; ++k) {
            int j = t + k * 512;
            if (j < lim) ibuf[j] = gsrc[j];
        }
    }
    __syncthreads();
    const int* myrow = ((const int*)lds) + t * 7;   // stride 7: conflict-free
    const int s0 = myrow[0];
    const int s1 = myrow[1];
    const int s2 = myrow[2];
    const int s3 = myrow[3];
    const int s4 = myrow[4];
    const int s5 = myrow[5];
    const int s6 = myrow[6];
    const int a7 = actions[bc];

    float v[8];
    {
        const float4* p = (const float4*)(V01 + s0 * NR + s1 * RR);
        float4 x = p[0], y = p[1];
        v[0] = x.x; v[1] = x.y; v[2] = x.z; v[3] = x.w;
        v[4] = y.x; v[5] = y.y; v[6] = y.z; v[7] = y.w;
    }

    STAGE(G2);
    GATHER(s2);
    STAGE(G3);
    GATHER(s3);
    STAGE(G4);
    GATHER(s4);
    STAGE(G5);
    GATHER(s5);

    // q = v . U67[s6][a7][:]
    const float4* p = (const float4*)(U67 + s6 * NR + a7 * RR);
    float4 x = p[0], y = p[1];
    float q = v[0] * x.x + v[1] * x.y + v[2] * x.z + v[3] * x.w
            + v[4] * y.x + v[5] * y.y + v[6] * y.z + v[7] * y.w;
    if (active) out[b] = q;
}

extern "C" void kernel_launch(void* const* d_in, const int* in_sizes, int n_in,
                              void* d_out, int out_size, void* d_ws, size_t ws_size,
                              hipStream_t stream) {
    const float* G0 = (const float*)d_in[0];
    const float* G1 = (const float*)d_in[1];
    const float* G2 = (const float*)d_in[2];
    const float* G3 = (const float*)d_in[3];
    const float* G4 = (const float*)d_in[4];
    const float* G5 = (const float*)d_in[5];
    const float* G6 = (const float*)d_in[6];
    const float* G7 = (const float*)d_in[7];
    const int* states  = (const int*)d_in[8];
    const int* actions = (const int*)d_in[9];
    float* out = (float*)d_out;
    int B = in_sizes[9];

    float* V01 = (float*)d_ws;            // 256*256*8 floats = 2 MB
    float* U67 = V01 + NN * NN * RR;      // 2 MB

    hipLaunchKernelGGL(build_tables, dim3(2 * NN), dim3(256), 0, stream,
                       G0, G1, G6, G7, V01, U67);

    int nblocks = (B + 511) / 512;
    hipLaunchKernelGGL(tt_main, dim3(nblocks), dim3(512), 0, stream,
                       G2, G3, G4, G5, V01, U67, states, actions, out, B);
}